// Round 3
// baseline (783.403 us; speedup 1.0000x reference)
//
#include <hip/hip_runtime.h>
#include <hip/hip_bf16.h>

#define NNODES 50000
#define NEDGES 800000
#define DF 128
#define KEXP 1280              // 10 planes * 128 (plane 9 = zero pad)
#define EPS 0.001f
#define GEMM_GRID 391          // ceil(50000/128)

typedef __bf16 bf16x8 __attribute__((ext_vector_type(8)));
typedef float  f32x4  __attribute__((ext_vector_type(4)));

// ---------------- weight pre-transform: Wt[o][k], k = c*128 + i ----------------
__global__ void build_wt(const float* __restrict__ bw,
                         const float* __restrict__ sw,
                         __bf16* __restrict__ wt) {
    int gid = blockIdx.x * 256 + threadIdx.x;      // exactly DF*KEXP threads
    int o = gid / KEXP;
    int k = gid - o * KEXP;
    int c = k >> 7, i = k & 127;
    float v = 0.0f;
    if (c == 0)      v = bw[o * DF + i];
    else if (c <= 8) v = sw[(o * DF + i) * 8 + (c - 1)];
    wt[gid] = (__bf16)v;
}

// ---------------- CSR build ----------------
__global__ void deg_count(const int* __restrict__ ei, int* __restrict__ deg) {
    int e = blockIdx.x * 256 + threadIdx.x;
    if (e >= NEDGES) return;
    atomicAdd(&deg[ei[NEDGES + e]], 1);
}

// one block: thread-serial chunks of 49 + single 1024-wide scan (few barriers)
#define SCHUNK 49
__global__ __launch_bounds__(1024) void scan_rowptr(const int* __restrict__ deg,
                                                    int* __restrict__ rowptr) {
    __shared__ int sums[1024];
    const int t = threadIdx.x;
    const int base = t * SCHUNK;
    int loc[SCHUNK];
    int s = 0;
#pragma unroll
    for (int j = 0; j < SCHUNK; ++j) {
        int i = base + j;
        int v = (i < NNODES) ? deg[i] : 0;
        loc[j] = s;                      // exclusive prefix within chunk
        s += v;
    }
    sums[t] = s;
    __syncthreads();
    for (int off = 1; off < 1024; off <<= 1) {
        int v = (t >= off) ? sums[t - off] : 0;
        __syncthreads();
        sums[t] += v;
        __syncthreads();
    }
    int excl = sums[t] - s;
#pragma unroll
    for (int j = 0; j < SCHUNK; ++j) {
        int i = base + j;
        if (i < NNODES) rowptr[i] = excl + loc[j];
    }
    if (t == 1023) rowptr[NNODES] = sums[1023];
}

__global__ void fill_csr(const int* __restrict__ ei, const int* __restrict__ deg,
                         const int* __restrict__ rowptr, int* __restrict__ cnt,
                         int* __restrict__ esrc, float* __restrict__ ew) {
    int e = blockIdx.x * 256 + threadIdx.x;
    if (e >= NEDGES) return;
    int s = ei[e];
    int d = ei[NEDGES + e];
    float w = rsqrtf((float)(deg[s] + 1)) * rsqrtf((float)(deg[d] + 1));
    int p = rowptr[d] + atomicAdd(&cnt[d], 1);
    esrc[p] = s;
    ew[p] = w;
}

// ---------------- aggregation: one 32-lane half-wave per node, no atomics ----
__global__ __launch_bounds__(256) void agg_gather(
        const int* __restrict__ rowptr, const int* __restrict__ esrc,
        const float* __restrict__ ew, const float* __restrict__ h,
        float* __restrict__ agg) {
    const int tid = blockIdx.x * 256 + threadIdx.x;   // (N*32) threads
    const int n = tid >> 5;
    const int l = tid & 31;
    if (n >= NNODES) return;
    int p  = rowptr[n];
    const int pe = rowptr[n + 1];
    f32x4 acc = {0.0f, 0.0f, 0.0f, 0.0f};
    for (; p + 1 < pe; p += 2) {
        int   s0 = esrc[p],  s1 = esrc[p + 1];
        float w0 = ew[p],    w1 = ew[p + 1];
        f32x4 v0 = *(const f32x4*)(h + (size_t)s0 * DF + l * 4);
        f32x4 v1 = *(const f32x4*)(h + (size_t)s1 * DF + l * 4);
        acc[0] += w0 * v0[0]; acc[1] += w0 * v0[1];
        acc[2] += w0 * v0[2]; acc[3] += w0 * v0[3];
        acc[0] += w1 * v1[0]; acc[1] += w1 * v1[1];
        acc[2] += w1 * v1[2]; acc[3] += w1 * v1[3];
    }
    if (p < pe) {
        int   s0 = esrc[p];
        float w0 = ew[p];
        f32x4 v0 = *(const f32x4*)(h + (size_t)s0 * DF + l * 4);
        acc[0] += w0 * v0[0]; acc[1] += w0 * v0[1];
        acc[2] += w0 * v0[2]; acc[3] += w0 * v0[3];
    }
    *(f32x4*)(agg + (size_t)n * DF + l * 4) = acc;
}

// ------- dual fused KAN gemm: blocks [0,391) do kanl(h)->hl, [391,782) kanc(agg)->hc
// double-buffered LDS, one barrier per K-chunk. hc may alias agg (block-private rows,
// all reads precede the epilogue store).
__global__ __launch_bounds__(256) void kan_gemm_dual(
        const float* __restrict__ h, const float* __restrict__ agg,
        const __bf16* __restrict__ wtl, const __bf16* __restrict__ wtc,
        float* hl, float* hc) {
    __shared__ __bf16 Alds[2][128 * 40];   // [buf][row][kk], row stride 40 (80B)
    __shared__ __bf16 Blds[2][128 * 40];

    const int g = blockIdx.x;
    const bool second = (g >= GEMM_GRID);
    const float*  hin = second ? agg : h;
    const __bf16* wt  = second ? wtc : wtl;
    float*        out = second ? hc  : hl;
    const int n0 = (second ? g - GEMM_GRID : g) * 128;

    const int tid  = threadIdx.x;
    const int lane = tid & 63;
    const int wv   = tid >> 6;
    const int wRow = wv >> 1, wCol = wv & 1;

    const int nloc = tid >> 1;          // expansion: row this thread fills
    const int half = tid & 1;           // which 8-wide i-half
    const int gRow = n0 + nloc;
    const int bo   = tid & 127;         // B staging: output column o
    const int bh   = tid >> 7;          // B staging: kk half (plane within pair)

    const int q   = lane >> 4;          // quad
    const int l15 = lane & 15;

    f32x4 acc[4][4] = {};

    float S[8], Wa[8], Wb[8], Wc[8], Wd[8];
    int IDX[8];

    auto compute_bases = [&](int ic) {
        const int i0 = ic * 16;
        float xv[8];
        if (gRow < NNODES) {
            f32x4 a = *(const f32x4*)(hin + (size_t)gRow * DF + i0 + half * 8);
            f32x4 b = *(const f32x4*)(hin + (size_t)gRow * DF + i0 + half * 8 + 4);
            xv[0]=a[0]; xv[1]=a[1]; xv[2]=a[2]; xv[3]=a[3];
            xv[4]=b[0]; xv[5]=b[1]; xv[6]=b[2]; xv[7]=b[3];
        } else {
#pragma unroll
            for (int j = 0; j < 8; ++j) xv[j] = 0.0f;
        }
#pragma unroll
        for (int j = 0; j < 8; ++j) {
            float x = xv[j];
            float f = (x + 2.2f) * 2.5f;       // (x - t0)/h, t0=-2.2, h=0.4
            float fi = floorf(f);
            IDX[j] = (int)fi;
            float u = f - fi;
            float u2 = u * u, u3 = u2 * u;
            float om = 1.0f - u;
            Wa[j] = u3 * (1.0f / 6.0f);
            Wb[j] = (((-3.0f * u + 3.0f) * u + 3.0f) * u + 1.0f) * (1.0f / 6.0f);
            Wc[j] = ((3.0f * u - 6.0f) * u2 + 4.0f) * (1.0f / 6.0f);
            Wd[j] = om * om * om * (1.0f / 6.0f);
            S[j]  = x / (1.0f + __expf(-x));   // silu
        }
    };

    auto stage = [&](int t, int buf) {         // chunk t = ic*5 + p
        const int ic = t / 5, p = t - ic * 5;
        const int i0 = ic * 16;
        const int c0 = 2 * p, c1 = c0 + 1;
        bf16x8 av0, av1;
#pragma unroll
        for (int j = 0; j < 8; ++j) {
            float v0, v1;
            if (c0 == 0) v0 = S[j];
            else {
                int tt = IDX[j] - (c0 - 1);
                v0 = (tt==0)?Wa[j]:(tt==1)?Wb[j]:(tt==2)?Wc[j]:(tt==3)?Wd[j]:0.0f;
            }
            if (c1 == 9) v1 = 0.0f;
            else {
                int tt = IDX[j] - (c1 - 1);
                v1 = (tt==0)?Wa[j]:(tt==1)?Wb[j]:(tt==2)?Wc[j]:(tt==3)?Wd[j]:0.0f;
            }
            av0[j] = (__bf16)v0;
            av1[j] = (__bf16)v1;
        }
        *(bf16x8*)&Alds[buf][nloc * 40 + half * 8]      = av0;
        *(bf16x8*)&Alds[buf][nloc * 40 + 16 + half * 8] = av1;
        const uint4* wp = (const uint4*)(wt + (size_t)bo * KEXP + (c0 + bh) * DF + i0);
        uint4 w0 = wp[0], w1 = wp[1];
        *(uint4*)&Blds[buf][bo * 40 + bh * 16]     = w0;
        *(uint4*)&Blds[buf][bo * 40 + bh * 16 + 8] = w1;
    };

    compute_bases(0);
    stage(0, 0);
    __syncthreads();

#pragma unroll 2
    for (int t = 0; t < 40; ++t) {
        const int buf = t & 1;
        if (t + 1 < 40) {
            if (((t + 1) % 5) == 0) compute_bases((t + 1) / 5);
            stage(t + 1, buf ^ 1);
        }
        bf16x8 aF[4], bF[4];
#pragma unroll
        for (int mi = 0; mi < 4; ++mi)
            aF[mi] = *(const bf16x8*)&Alds[buf][(wRow * 64 + mi * 16 + l15) * 40 + q * 8];
#pragma unroll
        for (int ni = 0; ni < 4; ++ni)
            bF[ni] = *(const bf16x8*)&Blds[buf][(wCol * 64 + ni * 16 + l15) * 40 + q * 8];
#pragma unroll
        for (int mi = 0; mi < 4; ++mi)
#pragma unroll
            for (int ni = 0; ni < 4; ++ni)
                acc[mi][ni] = __builtin_amdgcn_mfma_f32_16x16x32_bf16(
                    aF[mi], bF[ni], acc[mi][ni], 0, 0, 0);
        __syncthreads();
    }

    // epilogue: D layout row = q*4+r, col = lane&15 (m89-verified)
#pragma unroll
    for (int mi = 0; mi < 4; ++mi) {
#pragma unroll
        for (int ni = 0; ni < 4; ++ni) {
#pragma unroll
            for (int r = 0; r < 4; ++r) {
                int row = n0 + wRow * 64 + mi * 16 + q * 4 + r;
                int col = wCol * 64 + ni * 16 + l15;
                if (row < NNODES)
                    out[(size_t)row * DF + col] = acc[mi][ni][r];
            }
        }
    }
}

// ---------------- Euler combine: out = h + EPS*(hl + hc)  (in-place safe) -------
__global__ void euler_combine(const float* __restrict__ h,
                              const float* __restrict__ hl,
                              const float* __restrict__ hc,
                              float* out) {
    int i = blockIdx.x * 256 + threadIdx.x;
    if (i >= NNODES * DF / 4) return;
    f32x4 a = ((const f32x4*)h)[i];
    f32x4 b = ((const f32x4*)hl)[i];
    f32x4 c = ((const f32x4*)hc)[i];
    f32x4 r = {a[0] + EPS * (b[0] + c[0]), a[1] + EPS * (b[1] + c[1]),
               a[2] + EPS * (b[2] + c[2]), a[3] + EPS * (b[3] + c[3])};
    ((f32x4*)out)[i] = r;
}

extern "C" void kernel_launch(void* const* d_in, const int* in_sizes, int n_in,
                              void* d_out, int out_size, void* d_ws, size_t ws_size,
                              hipStream_t stream) {
    const float* x   = (const float*)d_in[0];
    const int*   ei  = (const int*)d_in[1];     // edge_index [2,E] int32
    const float* bwl = (const float*)d_in[2];
    const float* swl = (const float*)d_in[3];
    const float* bwc = (const float*)d_in[4];
    const float* swc = (const float*)d_in[5];
    float* out = (float*)d_out;

    char* ws = (char*)d_ws;
    int*    deg    = (int*)  (ws + 0);            //   200,000
    int*    cnt    = (int*)  (ws + 200192);       //   200,000
    int*    rowptr = (int*)  (ws + 400384);       //   200,004
    int*    esrc   = (int*)  (ws + 600448);       // 3,200,000
    float*  ew     = (float*)(ws + 3800448);      // 3,200,000
    float*  agg    = (float*)(ws + 7000448);      // 25,600,000  (hc aliases this)
    float*  hl     = (float*)(ws + 32600448);     // 25,600,000
    __bf16* wtl    = (__bf16*)(ws + 58200448);    //   327,680
    __bf16* wtc    = (__bf16*)(ws + 58528128);    //   327,680   (total ~58.9 MB)
    float*  hc     = agg;

    build_wt<<<(DF * KEXP) / 256, 256, 0, stream>>>(bwl, swl, wtl);
    build_wt<<<(DF * KEXP) / 256, 256, 0, stream>>>(bwc, swc, wtc);

    hipMemsetAsync(deg, 0, NNODES * sizeof(int), stream);
    hipMemsetAsync(cnt, 0, NNODES * sizeof(int), stream);
    deg_count<<<(NEDGES + 255) / 256, 256, 0, stream>>>(ei, deg);
    scan_rowptr<<<1, 1024, 0, stream>>>(deg, rowptr);
    fill_csr<<<(NEDGES + 255) / 256, 256, 0, stream>>>(ei, deg, rowptr, cnt, esrc, ew);

    const int comb_grid = (NNODES * DF / 4 + 255) / 256;   // 6250
    const float* h = x;
    for (int step = 0; step < 2; ++step) {                 // delta_t = 2
        agg_gather<<<(NNODES * 32 + 255) / 256, 256, 0, stream>>>(rowptr, esrc, ew, h, agg);
        kan_gemm_dual<<<2 * GEMM_GRID, 256, 0, stream>>>(h, agg, wtl, wtc, hl, hc);
        euler_combine<<<comb_grid, 256, 0, stream>>>(h, hl, hc, out);
        h = out;
    }
}